// Round 8
// baseline (250.824 us; speedup 1.0000x reference)
//
#include <hip/hip_runtime.h>
#include <math.h>

// Problem constants (match reference)
#define NQ 16384
#define NK 7933
#define DI 1024
#define HD 512
#define RANK_TARGET 11469   // NQ - int(0.3*NQ): 0-based ascending rank of thre

typedef __bf16 bf16x8 __attribute__((ext_vector_type(8)));
typedef float  f32x4  __attribute__((ext_vector_type(4)));

#define GLOAD_LDS16(g, l)                                                     \
  __builtin_amdgcn_global_load_lds(                                           \
      (const __attribute__((address_space(1))) void*)(g),                     \
      (__attribute__((address_space(3))) void*)(l), 16, 0, 0)

__device__ __forceinline__ unsigned mapf(float f) {
  unsigned b = __float_as_uint(f);
  return (b & 0x80000000u) ? ~b : (b | 0x80000000u);
}

__device__ __forceinline__ bf16x8 cvt8(float4 a, float4 b) {
  bf16x8 o;
  o[0] = (__bf16)a.x; o[1] = (__bf16)a.y; o[2] = (__bf16)a.z; o[3] = (__bf16)a.w;
  o[4] = (__bf16)b.x; o[5] = (__bf16)b.y; o[6] = (__bf16)b.z; o[7] = (__bf16)b.w;
  return o;
}

// ---------------------------------------------------------------------------
// Kernel 1: fp32 -> bf16 for wq_w, wk_w, key_x. Block 0 zeroes v/z/scf;
// blocks 1..64 zero A1dot/A1ss (128 KB). (query conv hidden in kernel 2.)
// ---------------------------------------------------------------------------
__global__ void conv_wk(const float* __restrict__ wq, const float* __restrict__ wk,
                        const float* __restrict__ key,
                        __bf16* __restrict__ wqbf, __bf16* __restrict__ wkbf,
                        __bf16* __restrict__ kbf, unsigned* __restrict__ zero_region,
                        uint2* __restrict__ a1zero) {
  if (blockIdx.x == 0) {
    for (int j = threadIdx.x; j < 1088; j += 256) zero_region[j] = 0u;
  } else if (blockIdx.x < 65) {
    int g = (blockIdx.x - 1) * 256 + threadIdx.x;   // 16384 uint2 = 128 KB
    uint2 zz; zz.x = 0u; zz.y = 0u;
    a1zero[g] = zz;
  }
  const int NK8 = NK * DI / 8;   // 1,015,424
  const int W8  = HD * DI / 8;   // 65,536
  const int total = NK8 + 2 * W8;
  int i = blockIdx.x * blockDim.x + threadIdx.x;
  int stride = gridDim.x * blockDim.x;
  for (; i < total; i += stride) {
    const float* s; __bf16* d; int j;
    if (i < NK8)            { s = key; d = kbf;  j = i; }
    else if (i < NK8 + W8)  { s = wq;  d = wqbf; j = i - NK8; }
    else                    { s = wk;  d = wkbf; j = i - NK8 - W8; }
    float4 a = ((const float4*)s)[2 * j];
    float4 b = ((const float4*)s)[2 * j + 1];
    ((bf16x8*)d)[j] = cvt8(a, b);
  }
}

// ---------------------------------------------------------------------------
// GEMM core (q path): C[M,512] = tanh(A_bf16 @ B_bf16^T + bias), 64x256 tile,
// 512 threads (8 waves, 2Mx4N), BK=64, dbuf LDS, all global_load_lds(16),
// XOR-swizzled, one barrier per K-step. FUSE_A1 epilogue: A1dot/A1ss atomics.
// (Identical to the r5/r7-passing kernel.)
// ---------------------------------------------------------------------------
template <bool FUSE_A1>
__device__ __forceinline__ void gemm_core(
    const __bf16* __restrict__ A, const __bf16* __restrict__ B,
    const float* __restrict__ bias, float* __restrict__ C, int M,
    int m0, int n0, __bf16* sA, __bf16* sB,
    const float* __restrict__ v, float* __restrict__ A1dot,
    float* __restrict__ A1ss) {
  constexpr int K = DI;
  constexpr int N = HD;
  const int tid  = threadIdx.x;
  const int lane = tid & 63;
  const int wave = tid >> 6;          // 0..7
  const int wr = wave >> 2;           // 0..1 (32-row groups)
  const int wc = wave & 3;            // 0..3 (64-col groups)

  const int srow = lane >> 3;                   // 0..7 row within segment
  const int scol = ((lane & 7) ^ srow) << 3;    // swizzled col (bf16 units)
  const int lrow = lane & 15;
  const int chi  = lane >> 4;                   // 0..3

  int gaA = m0 + wave * 8 + srow; if (gaA > M - 1) gaA = M - 1;
  const __bf16* Ap  = A + (size_t)gaA * K + scol;
  const __bf16* Bp0 = B + (size_t)(n0 + (wave * 4 + 0) * 8 + srow) * K + scol;
  const __bf16* Bp1 = B + (size_t)(n0 + (wave * 4 + 1) * 8 + srow) * K + scol;
  const __bf16* Bp2 = B + (size_t)(n0 + (wave * 4 + 2) * 8 + srow) * K + scol;
  const __bf16* Bp3 = B + (size_t)(n0 + (wave * 4 + 3) * 8 + srow) * K + scol;

  f32x4 acc[2][4] = {};

  GLOAD_LDS16(Ap,  &sA[wave * 512]);
  GLOAD_LDS16(Bp0, &sB[(wave * 4 + 0) * 512]);
  GLOAD_LDS16(Bp1, &sB[(wave * 4 + 1) * 512]);
  GLOAD_LDS16(Bp2, &sB[(wave * 4 + 2) * 512]);
  GLOAD_LDS16(Bp3, &sB[(wave * 4 + 3) * 512]);
  __syncthreads();

  int buf = 0;
  for (int t = 0; t < 16; ++t) {
    const int kk = t * 64;
    if (t < 15) {
      const int ob = (buf ^ 1);
      GLOAD_LDS16(Ap + kk + 64,  &sA[ob * 4096 + wave * 512]);
      GLOAD_LDS16(Bp0 + kk + 64, &sB[ob * 16384 + (wave * 4 + 0) * 512]);
      GLOAD_LDS16(Bp1 + kk + 64, &sB[ob * 16384 + (wave * 4 + 1) * 512]);
      GLOAD_LDS16(Bp2 + kk + 64, &sB[ob * 16384 + (wave * 4 + 2) * 512]);
      GLOAD_LDS16(Bp3 + kk + 64, &sB[ob * 16384 + (wave * 4 + 3) * 512]);
    }
    const __bf16* sAc = sA + buf * 4096;
    const __bf16* sBc = sB + buf * 16384;
#pragma unroll
    for (int ks = 0; ks < 64; ks += 32) {
      const int cc = (ks >> 3) + chi;
      const int sw = ((cc ^ (lrow & 7)) << 3);
      bf16x8 af[2], bfr[4];
      af[0] = *(const bf16x8*)(&sAc[(wr * 32 + lrow) * 64 + sw]);
      af[1] = *(const bf16x8*)(&sAc[(wr * 32 + 16 + lrow) * 64 + sw]);
#pragma unroll
      for (int ni = 0; ni < 4; ++ni)
        bfr[ni] = *(const bf16x8*)(&sBc[(wc * 64 + ni * 16 + lrow) * 64 + sw]);
#pragma unroll
      for (int ni = 0; ni < 4; ++ni) {
        acc[0][ni] = __builtin_amdgcn_mfma_f32_16x16x32_bf16(af[0], bfr[ni], acc[0][ni], 0, 0, 0);
        acc[1][ni] = __builtin_amdgcn_mfma_f32_16x16x32_bf16(af[1], bfr[ni], acc[1][ni], 0, 0, 0);
      }
    }
    if (t < 15) {
      __syncthreads();
      buf ^= 1;
    }
  }

  // C/D layout: row = (lane>>4)*4 + reg, col = lane&15  [learn_hip m89]
  const int rbase = m0 + wr * 32 + ((lane >> 4) << 2);
  const int cbase = n0 + wc * 64 + (lane & 15);
  float b4[4], v4[4];
#pragma unroll
  for (int ni = 0; ni < 4; ++ni) {
    b4[ni] = bias[cbase + ni * 16];
    if constexpr (FUSE_A1) v4[ni] = v[cbase + ni * 16];
  }
#pragma unroll
  for (int mi = 0; mi < 2; ++mi) {
#pragma unroll
    for (int r = 0; r < 4; ++r) {
      int grow = rbase + mi * 16 + r;
      if (grow < M) {
        float pd = 0.f, pss = 0.f;
#pragma unroll
        for (int ni = 0; ni < 4; ++ni) {
          float val = tanhf(acc[mi][ni][r] + b4[ni]);
          C[(size_t)grow * N + cbase + ni * 16] = val;
          if constexpr (FUSE_A1) { pd += val * v4[ni]; pss += val * val; }
        }
        if constexpr (FUSE_A1) {
#pragma unroll
          for (int off = 1; off < 16; off <<= 1) {
            pd += __shfl_xor(pd, off);
            pss += __shfl_xor(pss, off);
          }
          if ((lane & 15) == 0) {
            atomicAdd(&A1dot[grow], pd);
            atomicAdd(&A1ss[grow], pss);
          }
        }
      }
    }
  }
}

// ---------------------------------------------------------------------------
// Kernel 2: blocks 0..123: k-GEMM tile 64x512 (full HD) with FUSED v epilogue
// (ktanh never touches HBM). Blocks 124..511: query fp32 -> bf16.
// LDS 80 KB (sA dbuf 16K + sB single 64K) -> 2 blocks/CU: each GEMM block can
// co-reside with a conv block whose streaming waves cover the B-stage stall.
// ---------------------------------------------------------------------------
__global__ __launch_bounds__(512, 4)
void gemm_k_fused(const __bf16* __restrict__ kbf, const __bf16* __restrict__ wkbf,
                  const float* __restrict__ wk_b, const float* __restrict__ wa,
                  float* __restrict__ v,
                  const float* __restrict__ query, __bf16* __restrict__ qbf) {
  __shared__ __align__(16) __bf16 sA[2 * 64 * 64];     // 16 KB (dbuf)
  __shared__ __align__(16) __bf16 sB[512 * 64];        // 64 KB (single)
  __shared__ float ssrow[64];
  const int bid = blockIdx.x;
  const int tid = threadIdx.x;

  if (bid >= 124) {
    // query conversion, overlapped with the GEMM blocks (co-resident, 2/CU)
    const int total = NQ * DI / 8;                     // 2,097,152 chunks
    for (int i = (bid - 124) * 512 + tid; i < total; i += 388 * 512) {
      float4 a = ((const float4*)query)[2 * i];
      float4 b = ((const float4*)query)[2 * i + 1];
      ((bf16x8*)qbf)[i] = cvt8(a, b);
    }
    return;
  }

  constexpr int K = DI;
  const int lane = tid & 63;
  const int wave = tid >> 6;              // 0..7; wave owns cols wave*64..+63
  const int m0 = bid * 64;

  const int srow = lane >> 3;
  const int scol = ((lane & 7) ^ srow) << 3;
  const int lrow = lane & 15;
  const int chi  = lane >> 4;

  int gaA = m0 + wave * 8 + srow; if (gaA > NK - 1) gaA = NK - 1;
  const __bf16* Ap = kbf + (size_t)gaA * K + scol;
  const __bf16* Bp[8];
#pragma unroll
  for (int c = 0; c < 8; ++c)
    Bp[c] = wkbf + (size_t)(wave * 64 + c * 8 + srow) * K + scol;

  f32x4 acc[4][4] = {};

  // prologue: stage A0 (dbuf slot 0) + B0 (single buffer)
  GLOAD_LDS16(Ap, &sA[wave * 512]);
#pragma unroll
  for (int c = 0; c < 8; ++c)
    GLOAD_LDS16(Bp[c], &sB[(wave * 8 + c) * 512]);
  __syncthreads();

  int buf = 0;
  for (int t = 0; t < 16; ++t) {
    const int kk = t * 64;
    if (t < 15)  // A prefetch: fire-and-forget into the other sA slot
      GLOAD_LDS16(Ap + kk + 64, &sA[(buf ^ 1) * 4096 + wave * 512]);
    const __bf16* sAc = sA + buf * 4096;
#pragma unroll
    for (int ks = 0; ks < 64; ks += 32) {
      const int cc = (ks >> 3) + chi;
      const int sw = ((cc ^ (lrow & 7)) << 3);
      bf16x8 af[4], bfr[4];
#pragma unroll
      for (int mi = 0; mi < 4; ++mi)
        af[mi] = *(const bf16x8*)(&sAc[(mi * 16 + lrow) * 64 + sw]);
#pragma unroll
      for (int ni = 0; ni < 4; ++ni)
        bfr[ni] = *(const bf16x8*)(&sB[(wave * 64 + ni * 16 + lrow) * 64 + sw]);
#pragma unroll
      for (int mi = 0; mi < 4; ++mi)
#pragma unroll
        for (int ni = 0; ni < 4; ++ni)
          acc[mi][ni] = __builtin_amdgcn_mfma_f32_16x16x32_bf16(af[mi], bfr[ni], acc[mi][ni], 0, 0, 0);
    }
    if (t < 15) {
      __syncthreads();                 // all waves done reading sB; A(t+1) landed
#pragma unroll
      for (int c = 0; c < 8; ++c)      // overwrite sB with B(t+1)
        GLOAD_LDS16(Bp[c] + kk + 64, &sB[(wave * 8 + c) * 512]);
      __syncthreads();                 // B(t+1) resident
      buf ^= 1;
    }
  }

  // ---- fused epilogue: tanh, row-norm, v accumulation (no ktanh store) ----
  __syncthreads();                     // compute done before ssrow reuse
  if (tid < 64) ssrow[tid] = 0.f;
  __syncthreads();

  float b4[4];
#pragma unroll
  for (int ni = 0; ni < 4; ++ni) b4[ni] = wk_b[wave * 64 + ni * 16 + lrow];

#pragma unroll
  for (int mi = 0; mi < 4; ++mi)
#pragma unroll
    for (int ni = 0; ni < 4; ++ni)
#pragma unroll
      for (int r = 0; r < 4; ++r)
        acc[mi][ni][r] = tanhf(acc[mi][ni][r] + b4[ni]);

  // per-row sum of squares (this wave's 64-col slice), 16-lane reduce
#pragma unroll
  for (int mi = 0; mi < 4; ++mi)
#pragma unroll
    for (int r = 0; r < 4; ++r) {
      float ps = 0.f;
#pragma unroll
      for (int ni = 0; ni < 4; ++ni) ps += acc[mi][ni][r] * acc[mi][ni][r];
#pragma unroll
      for (int off = 1; off < 16; off <<= 1) ps += __shfl_xor(ps, off);
      if ((lane & 15) == 0)
        atomicAdd(&ssrow[mi * 16 + (lane >> 4) * 4 + r], ps);
    }
  __syncthreads();

  if (tid < 64) {
    int grow = m0 + tid;
    float s = 0.f;
    if (grow < NK) s = wa[grow] / fmaxf(sqrtf(ssrow[tid]), 1e-12f);
    ssrow[tid] = s;                      // replace ss with scale (0 for tail)
  }
  __syncthreads();

  float sc[4][4];
#pragma unroll
  for (int mi = 0; mi < 4; ++mi)
#pragma unroll
    for (int r = 0; r < 4; ++r)
      sc[mi][r] = ssrow[mi * 16 + (lane >> 4) * 4 + r];

#pragma unroll
  for (int ni = 0; ni < 4; ++ni) {
    float cs = 0.f;
#pragma unroll
    for (int mi = 0; mi < 4; ++mi)
#pragma unroll
      for (int r = 0; r < 4; ++r)
        cs += acc[mi][ni][r] * sc[mi][r];
    cs += __shfl_xor(cs, 16);
    cs += __shfl_xor(cs, 32);
    if (lane < 16) atomicAdd(&v[wave * 64 + ni * 16 + lane], cs);
  }
}

// ---------------------------------------------------------------------------
// Kernel 3: qtanh = tanh(qbf @ wqbf^T + wq_b) with fused A1 partial dot/ss.
// ---------------------------------------------------------------------------
__global__ __launch_bounds__(512, 4)
void gemm_q(const __bf16* __restrict__ qbf, const __bf16* __restrict__ wqbf,
            const float* __restrict__ wq_b, float* __restrict__ qtanh,
            const float* __restrict__ v, float* __restrict__ A1dot,
            float* __restrict__ A1ss) {
  __shared__ __align__(16) __bf16 sA[2 * 64 * 64];
  __shared__ __align__(16) __bf16 sB[2 * 256 * 64];
  gemm_core<true>(qbf, wqbf, wq_b, qtanh, NQ, blockIdx.x * 64, blockIdx.y * 256,
                  sA, sB, v, A1dot, A1ss);
}

// ---------------------------------------------------------------------------
// Kernel 4: single block, 1024 threads. Finalize A1 from A1dot/A1ss, then
// exact rank-11469 select via 16 rounds of 2-bit greedy MSB binary search.
// ---------------------------------------------------------------------------
__global__ __launch_bounds__(1024)
void select_kernel(const float* __restrict__ A1dot, const float* __restrict__ A1ss,
                   const float* __restrict__ wa_b, float* __restrict__ A1,
                   float* __restrict__ scf) {
  __shared__ unsigned wred1[16], wred2[16], wred3[16];
  __shared__ unsigned s_res;
  const int t = threadIdx.x, lane = t & 63, wave = t >> 6;
  const float wab = wa_b[0];
  unsigned kloc[16];
#pragma unroll 4
  for (int j = 0; j < 16; ++j) {
    int i = j * 1024 + t;
    float d = A1dot[i], ss = A1ss[i];
    float a1 = d / fmaxf(sqrtf(ss), 1e-12f) + wab;
    A1[i] = a1;
    kloc[j] = mapf(a1);
  }
  if (t == 0) s_res = 0u;
  __syncthreads();

  for (int b = 30; b >= 0; b -= 2) {
    const unsigned res = s_res;
    const unsigned t1 = res | (1u << b);
    const unsigned t2 = res | (2u << b);
    const unsigned t3 = res | (3u << b);
    unsigned c1 = 0, c2 = 0, c3 = 0;
#pragma unroll
    for (int j = 0; j < 16; ++j) {
      unsigned k = kloc[j];
      c1 += (k < t1); c2 += (k < t2); c3 += (k < t3);
    }
#pragma unroll
    for (int off = 32; off; off >>= 1) {
      c1 += __shfl_xor(c1, off);
      c2 += __shfl_xor(c2, off);
      c3 += __shfl_xor(c3, off);
    }
    if (lane == 0) { wred1[wave] = c1; wred2[wave] = c2; wred3[wave] = c3; }
    __syncthreads();
    if (t == 0) {
      unsigned C1 = 0, C2 = 0, C3 = 0;
      for (int w = 0; w < 16; ++w) { C1 += wred1[w]; C2 += wred2[w]; C3 += wred3[w]; }
      unsigned nr = res;
      if (C3 <= RANK_TARGET)      nr = t3;
      else if (C2 <= RANK_TARGET) nr = t2;
      else if (C1 <= RANK_TARGET) nr = t1;
      s_res = nr;
    }
    __syncthreads();
  }
  if (t == 0) {
    unsigned key = s_res;
    unsigned bits = (key & 0x80000000u) ? (key ^ 0x80000000u) : ~key;
    scf[0] = __uint_as_float(bits);
  }
}

// ---------------------------------------------------------------------------
// Kernel 5: e(r) = exp(thr(A1[r]) - thre) -> out_attn (unnormalized);
// z'[c] += e(r)*qt[r,c]; S += e(r) into scf[2].
// ---------------------------------------------------------------------------
__global__ __launch_bounds__(256)
void expz(const float* __restrict__ A1, const float* __restrict__ qt,
          float* __restrict__ scf, float* __restrict__ e_out,
          float* __restrict__ z) {
  __shared__ float vpart[4][512];
  __shared__ float esum[4];
  const int tid = threadIdx.x, lane = tid & 63, wave = tid >> 6;
  const float thre = scf[0];
  const int gw = blockIdx.x * 4 + wave;
  const int tw = gridDim.x * 4;
  float acc[8] = {0, 0, 0, 0, 0, 0, 0, 0};
  float es = 0.f;
  for (int r = gw; r < NQ; r += tw) {
    float x = A1[r]; x = (x > thre) ? x : 0.f;
    float e = expf(x - thre);
    if (lane == 0) e_out[r] = e;
    es += e;
    const float4* p = (const float4*)(qt + (size_t)r * HD + lane * 8);
    float4 u = p[0], w = p[1];
    acc[0] += e * u.x; acc[1] += e * u.y; acc[2] += e * u.z; acc[3] += e * u.w;
    acc[4] += e * w.x; acc[5] += e * w.y; acc[6] += e * w.z; acc[7] += e * w.w;
  }
  if (lane == 0) esum[wave] = es;   // es identical across lanes of the wave
#pragma unroll
  for (int j = 0; j < 8; ++j) vpart[wave][lane * 8 + j] = acc[j];
  __syncthreads();
  for (int c = tid; c < 512; c += 256)
    atomicAdd(&z[c], vpart[0][c] + vpart[1][c] + vpart[2][c] + vpart[3][c]);
  if (tid == 0) atomicAdd(&scf[2], esum[0] + esum[1] + esum[2] + esum[3]);
}

// ---------------------------------------------------------------------------
// Kernel 6: attn *= 1/S (blocks 0..63); block 64: y = (z'.cls_w)/S + cls_b.
// ---------------------------------------------------------------------------
__global__ __launch_bounds__(256)
void finalize(float* __restrict__ attn, const float* __restrict__ scf,
              const float* __restrict__ z, const float* __restrict__ cls_w,
              const float* __restrict__ cls_b, float* __restrict__ y) {
  const float invZ = 1.f / scf[2];
  if (blockIdx.x < 64) {
    int i = blockIdx.x * 256 + threadIdx.x;
    attn[i] *= invZ;
  } else if (threadIdx.x < 64) {
    const int lane = threadIdx.x;
    const float4* zp = (const float4*)(z + lane * 8);
    const float4* wp = (const float4*)(cls_w + lane * 8);
    float4 a = zp[0], b = zp[1], c = wp[0], d = wp[1];
    float dot = a.x * c.x + a.y * c.y + a.z * c.z + a.w * c.w
              + b.x * d.x + b.y * d.y + b.z * d.z + b.w * d.w;
#pragma unroll
    for (int off = 32; off; off >>= 1) dot += __shfl_xor(dot, off);
    if (lane == 0) y[0] = dot * invZ + cls_b[0];
  }
}

// ---------------------------------------------------------------------------
// Workspace layout (bytes). Max end = 88,211,456. No overlays.
// ---------------------------------------------------------------------------
#define OFF_WQBF 0u
#define OFF_WKBF 1048576u
#define OFF_QBF  2097152u      // 33.55 MB, ends 35,651,584
#define OFF_A1   35651584u     // 64 KB
#define OFF_V    35717120u     // 2 KB
#define OFF_Z    35719168u     // 2 KB
#define OFF_SC   35721216u     // 256 B
#define OFF_KBF  35721472u     // 16.25 MB, ends 51,968,256
#define OFF_QT   52428800u     // 33.55 MB, ends 85,983,232
#define OFF_A1D  88080384u     // 64 KB
#define OFF_A1S  88145920u     // 64 KB, ends 88,211,456

extern "C" void kernel_launch(void* const* d_in, const int* in_sizes, int n_in,
                              void* d_out, int out_size, void* d_ws, size_t ws_size,
                              hipStream_t stream) {
  const float* query = (const float*)d_in[0];
  const float* key_x = (const float*)d_in[1];
  const float* wq_w  = (const float*)d_in[2];
  const float* wq_b  = (const float*)d_in[3];
  const float* wk_w  = (const float*)d_in[4];
  const float* wk_b  = (const float*)d_in[5];
  const float* wa_w  = (const float*)d_in[6];
  const float* wa_b  = (const float*)d_in[7];
  const float* cls_w = (const float*)d_in[8];
  const float* cls_b = (const float*)d_in[9];
  float* out = (float*)d_out;

  char* ws = (char*)d_ws;
  __bf16* wqbf  = (__bf16*)(ws + OFF_WQBF);
  __bf16* wkbf  = (__bf16*)(ws + OFF_WKBF);
  __bf16* qbf   = (__bf16*)(ws + OFF_QBF);
  float*  A1    = (float*)(ws + OFF_A1);
  float*  v     = (float*)(ws + OFF_V);
  float*  z     = (float*)(ws + OFF_Z);
  float*  scf   = (float*)(ws + OFF_SC);
  __bf16* kbf   = (__bf16*)(ws + OFF_KBF);
  float*  qtanh = (float*)(ws + OFF_QT);
  float*  A1dot = (float*)(ws + OFF_A1D);
  float*  A1ss  = (float*)(ws + OFF_A1S);
  float*  out_attn = out + 1;

  // 1: convert key + weights to bf16; zero v/z/scf + A1dot/A1ss
  conv_wk<<<2048, 256, 0, stream>>>(wq_w, wk_w, key_x, wqbf, wkbf, kbf,
                                    (unsigned*)v, (uint2*)A1dot);

  // 2: k-GEMM (64x512 tiles, 80 KB LDS, 2 blocks/CU) with fused v epilogue
  //    || query -> qbf on co-resident conv blocks
  gemm_k_fused<<<512, 512, 0, stream>>>(kbf, wkbf, wk_b, wa_w, v, query, qbf);

  // 3: qtanh = tanh(qbf @ wqbf^T + wq_b) with fused A1 partial dot/ss
  gemm_q<<<dim3(256, 2), 512, 0, stream>>>(qbf, wqbf, wq_b, qtanh, v, A1dot, A1ss);

  // 4: finalize A1 + exact rank-11469 threshold (single block)
  select_kernel<<<1, 1024, 0, stream>>>(A1dot, A1ss, wa_b, A1, scf);

  // 5: e(r), z' accumulation, S
  expz<<<256, 256, 0, stream>>>(A1, qtanh, scf, out_attn, z);

  // 6: normalize attn; y
  finalize<<<65, 256, 0, stream>>>(out_attn, scf, z, cls_w, cls_b, out);
}

// Round 9
// 243.838 us; speedup vs baseline: 1.0286x; 1.0286x over previous
//
#include <hip/hip_runtime.h>
#include <math.h>

// Problem constants (match reference)
#define NQ 16384
#define NK 7933
#define DI 1024
#define HD 512
#define RANK_TARGET 11469   // NQ - int(0.3*NQ): 0-based ascending rank of thre

typedef __bf16 bf16x8 __attribute__((ext_vector_type(8)));
typedef float  f32x4  __attribute__((ext_vector_type(4)));

#define GLOAD_LDS16(g, l)                                                     \
  __builtin_amdgcn_global_load_lds(                                           \
      (const __attribute__((address_space(1))) void*)(g),                     \
      (__attribute__((address_space(3))) void*)(l), 16, 0, 0)

__device__ __forceinline__ unsigned mapf(float f) {
  unsigned b = __float_as_uint(f);
  return (b & 0x80000000u) ? ~b : (b | 0x80000000u);
}

__device__ __forceinline__ bf16x8 cvt8(float4 a, float4 b) {
  bf16x8 o;
  o[0] = (__bf16)a.x; o[1] = (__bf16)a.y; o[2] = (__bf16)a.z; o[3] = (__bf16)a.w;
  o[4] = (__bf16)b.x; o[5] = (__bf16)b.y; o[6] = (__bf16)b.z; o[7] = (__bf16)b.w;
  return o;
}

// ---------------------------------------------------------------------------
// Kernel 1: fp32 -> bf16 for wq_w, wk_w, key_x ONLY (query is consumed fp32
// directly by the mega kernel's q path). Block 0 zeroes v/z/scf.
// ---------------------------------------------------------------------------
__global__ void conv_wk(const float* __restrict__ wq, const float* __restrict__ wk,
                        const float* __restrict__ key,
                        __bf16* __restrict__ wqbf, __bf16* __restrict__ wkbf,
                        __bf16* __restrict__ kbf, unsigned* __restrict__ zero_region) {
  if (blockIdx.x == 0) {
    for (int j = threadIdx.x; j < 1088; j += 256) zero_region[j] = 0u;
  }
  const int NK8 = NK * DI / 8;   // 1,015,424
  const int W8  = HD * DI / 8;   // 65,536
  const int total = NK8 + 2 * W8;
  int i = blockIdx.x * blockDim.x + threadIdx.x;
  int stride = gridDim.x * blockDim.x;
  for (; i < total; i += stride) {
    const float* s; __bf16* d; int j;
    if (i < NK8)            { s = key; d = kbf;  j = i; }
    else if (i < NK8 + W8)  { s = wq;  d = wqbf; j = i - NK8; }
    else                    { s = wk;  d = wkbf; j = i - NK8 - W8; }
    float4 a = ((const float4*)s)[2 * j];
    float4 b = ((const float4*)s)[2 * j + 1];
    ((bf16x8*)d)[j] = cvt8(a, b);
  }
}

// ---------------------------------------------------------------------------
// Mega kernel, 636 blocks x 512 threads, 80 KB LDS (= exactly 81920 B ->
// 2 blocks/CU). Blocks 0..123: k-GEMM 64x512 with fused v epilogue (no ktanh
// to HBM; ssrow aliased onto dead sA). Blocks 124..635: q-GEMM 64x256 tiles
// reading fp32 query directly (r3-proven reg-staged A: load early, cvt+
// ds_write late), writing qtanh only — A1 moved to a later BW pass.
// The two groups are independent; q blocks backfill k's staging stalls.
// ---------------------------------------------------------------------------
__global__ __launch_bounds__(512, 4)
void mega_gemms(const __bf16* __restrict__ kbf, const __bf16* __restrict__ wkbf,
                const float* __restrict__ wk_b, const float* __restrict__ wa,
                float* __restrict__ v,
                const float* __restrict__ query, const __bf16* __restrict__ wqbf,
                const float* __restrict__ wq_b, float* __restrict__ qtanh) {
  __shared__ __align__(16) char smem[81920];
  const int bid = blockIdx.x;
  const int tid = threadIdx.x;
  const int lane = tid & 63;
  const int wave = tid >> 6;                    // 0..7
  const int srow = lane >> 3;                   // 0..7 row within segment
  const int scol = ((lane & 7) ^ srow) << 3;    // swizzled col (bf16 units)
  const int lrow = lane & 15;
  const int chi  = lane >> 4;                   // 0..3
  constexpr int K = DI;

  if (bid < 124) {
    // ---------------- k path: 64x512 tile, fused v epilogue ----------------
    __bf16* sA = (__bf16*)smem;                 // 2 x 4096 elems (16 KB dbuf)
    __bf16* sB = (__bf16*)(smem + 16384);       // 32768 elems (64 KB single)
    float* ssrow = (float*)smem;                // aliases sA (dead after K-loop)
    const int m0 = bid * 64;

    int gaA = m0 + wave * 8 + srow; if (gaA > NK - 1) gaA = NK - 1;
    const __bf16* Ap = kbf + (size_t)gaA * K + scol;
    const __bf16* Bp[8];
#pragma unroll
    for (int c = 0; c < 8; ++c)
      Bp[c] = wkbf + (size_t)(wave * 64 + c * 8 + srow) * K + scol;

    f32x4 acc[4][4] = {};

    GLOAD_LDS16(Ap, &sA[wave * 512]);
#pragma unroll
    for (int c = 0; c < 8; ++c)
      GLOAD_LDS16(Bp[c], &sB[(wave * 8 + c) * 512]);
    __syncthreads();

    int buf = 0;
    for (int t = 0; t < 16; ++t) {
      const int kk = t * 64;
      if (t < 15)
        GLOAD_LDS16(Ap + kk + 64, &sA[(buf ^ 1) * 4096 + wave * 512]);
      const __bf16* sAc = sA + buf * 4096;
#pragma unroll
      for (int ks = 0; ks < 64; ks += 32) {
        const int cc = (ks >> 3) + chi;
        const int sw = ((cc ^ (lrow & 7)) << 3);
        bf16x8 af[4], bfr[4];
#pragma unroll
        for (int mi = 0; mi < 4; ++mi)
          af[mi] = *(const bf16x8*)(&sAc[(mi * 16 + lrow) * 64 + sw]);
#pragma unroll
        for (int ni = 0; ni < 4; ++ni)
          bfr[ni] = *(const bf16x8*)(&sB[(wave * 64 + ni * 16 + lrow) * 64 + sw]);
#pragma unroll
        for (int mi = 0; mi < 4; ++mi)
#pragma unroll
          for (int ni = 0; ni < 4; ++ni)
            acc[mi][ni] = __builtin_amdgcn_mfma_f32_16x16x32_bf16(af[mi], bfr[ni], acc[mi][ni], 0, 0, 0);
      }
      if (t < 15) {
        __syncthreads();                 // sB readers done; A(t+1) landed
#pragma unroll
        for (int c = 0; c < 8; ++c)      // overwrite sB with B(t+1)
          GLOAD_LDS16(Bp[c] + kk + 64, &sB[(wave * 8 + c) * 512]);
        __syncthreads();                 // B(t+1) resident
        buf ^= 1;
      }
    }

    // fused epilogue: tanh, row-norm, v accumulation (no ktanh store)
    __syncthreads();                     // all sA reads retired before aliasing
    if (tid < 64) ssrow[tid] = 0.f;
    __syncthreads();

    float b4[4];
#pragma unroll
    for (int ni = 0; ni < 4; ++ni) b4[ni] = wk_b[wave * 64 + ni * 16 + lrow];

#pragma unroll
    for (int mi = 0; mi < 4; ++mi)
#pragma unroll
      for (int ni = 0; ni < 4; ++ni)
#pragma unroll
        for (int r = 0; r < 4; ++r)
          acc[mi][ni][r] = tanhf(acc[mi][ni][r] + b4[ni]);

#pragma unroll
    for (int mi = 0; mi < 4; ++mi)
#pragma unroll
      for (int r = 0; r < 4; ++r) {
        float ps = 0.f;
#pragma unroll
        for (int ni = 0; ni < 4; ++ni) ps += acc[mi][ni][r] * acc[mi][ni][r];
#pragma unroll
        for (int off = 1; off < 16; off <<= 1) ps += __shfl_xor(ps, off);
        if ((lane & 15) == 0)
          atomicAdd(&ssrow[mi * 16 + (lane >> 4) * 4 + r], ps);
      }
    __syncthreads();

    if (tid < 64) {
      int grow = m0 + tid;
      float s = 0.f;
      if (grow < NK) s = wa[grow] / fmaxf(sqrtf(ssrow[tid]), 1e-12f);
      ssrow[tid] = s;                    // replace ss with scale (0 for tail)
    }
    __syncthreads();

    float sc[4][4];
#pragma unroll
    for (int mi = 0; mi < 4; ++mi)
#pragma unroll
      for (int r = 0; r < 4; ++r)
        sc[mi][r] = ssrow[mi * 16 + (lane >> 4) * 4 + r];

#pragma unroll
    for (int ni = 0; ni < 4; ++ni) {
      float cs = 0.f;
#pragma unroll
      for (int mi = 0; mi < 4; ++mi)
#pragma unroll
        for (int r = 0; r < 4; ++r)
          cs += acc[mi][ni][r] * sc[mi][r];
      cs += __shfl_xor(cs, 16);
      cs += __shfl_xor(cs, 32);
      if (lane < 16) atomicAdd(&v[wave * 64 + ni * 16 + lane], cs);
    }
  } else {
    // ---------------- q path: 64x256 tile, fp32 A from global --------------
    __bf16* sA = (__bf16*)smem;                 // 2 x 4096 elems (16 KB dbuf)
    __bf16* sB = (__bf16*)(smem + 16384);       // 2 x 16384 elems (64 KB dbuf)
    const int qi = bid - 124;                   // 0..511
    const int m0 = (qi >> 1) * 64;
    const int n0 = (qi & 1) * 256;
    const int wr = wave >> 2;                   // 0..1
    const int wc = wave & 3;                    // 0..3

    // A reg-stage mapping: thread -> (row, 8-float chunk), swizzled LDS slot
    const int arow = tid >> 3;                  // 0..63
    const int acb  = tid & 7;                   // 0..7
    const int aoff = arow * 64 + ((acb ^ (arow & 7)) << 3);
    const float* ap = query + (size_t)(m0 + arow) * K + acb * 8;

    const __bf16* Bp0 = wqbf + (size_t)(n0 + (wave * 4 + 0) * 8 + srow) * K + scol;
    const __bf16* Bp1 = wqbf + (size_t)(n0 + (wave * 4 + 1) * 8 + srow) * K + scol;
    const __bf16* Bp2 = wqbf + (size_t)(n0 + (wave * 4 + 2) * 8 + srow) * K + scol;
    const __bf16* Bp3 = wqbf + (size_t)(n0 + (wave * 4 + 3) * 8 + srow) * K + scol;

    f32x4 acc[2][4] = {};

    {  // prologue: stage tile 0
      float4 x0 = *(const float4*)(ap);
      float4 x1 = *(const float4*)(ap + 4);
      GLOAD_LDS16(Bp0, &sB[(wave * 4 + 0) * 512]);
      GLOAD_LDS16(Bp1, &sB[(wave * 4 + 1) * 512]);
      GLOAD_LDS16(Bp2, &sB[(wave * 4 + 2) * 512]);
      GLOAD_LDS16(Bp3, &sB[(wave * 4 + 3) * 512]);
      *(bf16x8*)&sA[aoff] = cvt8(x0, x1);
      __syncthreads();
    }

    int buf = 0;
    for (int t = 0; t < 16; ++t) {
      const int kk = t * 64;
      float4 x0, x1;
      if (t < 15) {
        x0 = *(const float4*)(ap + kk + 64);     // A loads first (oldest VMEM)
        x1 = *(const float4*)(ap + kk + 68);
        const int ob = buf ^ 1;
        GLOAD_LDS16(Bp0 + kk + 64, &sB[ob * 16384 + (wave * 4 + 0) * 512]);
        GLOAD_LDS16(Bp1 + kk + 64, &sB[ob * 16384 + (wave * 4 + 1) * 512]);
        GLOAD_LDS16(Bp2 + kk + 64, &sB[ob * 16384 + (wave * 4 + 2) * 512]);
        GLOAD_LDS16(Bp3 + kk + 64, &sB[ob * 16384 + (wave * 4 + 3) * 512]);
      }
      const __bf16* sAc = sA + buf * 4096;
      const __bf16* sBc = sB + buf * 16384;
#pragma unroll
      for (int ks = 0; ks < 64; ks += 32) {
        const int cc = (ks >> 3) + chi;
        const int sw = ((cc ^ (lrow & 7)) << 3);
        bf16x8 af[2], bfr[4];
        af[0] = *(const bf16x8*)(&sAc[(wr * 32 + lrow) * 64 + sw]);
        af[1] = *(const bf16x8*)(&sAc[(wr * 32 + 16 + lrow) * 64 + sw]);
#pragma unroll
        for (int ni = 0; ni < 4; ++ni)
          bfr[ni] = *(const bf16x8*)(&sBc[(wc * 64 + ni * 16 + lrow) * 64 + sw]);
#pragma unroll
        for (int ni = 0; ni < 4; ++ni) {
          acc[0][ni] = __builtin_amdgcn_mfma_f32_16x16x32_bf16(af[0], bfr[ni], acc[0][ni], 0, 0, 0);
          acc[1][ni] = __builtin_amdgcn_mfma_f32_16x16x32_bf16(af[1], bfr[ni], acc[1][ni], 0, 0, 0);
        }
      }
      if (t < 15) {
        *(bf16x8*)&sA[(buf ^ 1) * 4096 + aoff] = cvt8(x0, x1);  // waits A regs
        __syncthreads();                  // retires B prefetch + sA write
        buf ^= 1;
      }
    }

    // epilogue: qtanh only (A1 handled by a1_pass)
    const int rbase = m0 + wr * 32 + ((lane >> 4) << 2);
    const int cbase = n0 + wc * 64 + (lane & 15);
    float b4[4];
#pragma unroll
    for (int ni = 0; ni < 4; ++ni) b4[ni] = wq_b[cbase + ni * 16];
#pragma unroll
    for (int mi = 0; mi < 2; ++mi)
#pragma unroll
      for (int r = 0; r < 4; ++r) {
        int grow = rbase + mi * 16 + r;
#pragma unroll
        for (int ni = 0; ni < 4; ++ni)
          qtanh[(size_t)grow * HD + cbase + ni * 16] =
              tanhf(acc[mi][ni][r] + b4[ni]);
      }
  }
}

// ---------------------------------------------------------------------------
// Kernel 3: A1[r] = (qtanh[r]·v)/max(||qtanh[r]||,1e-12) + wa_b.
// 512 blocks x 256 threads; one row per wave, grid-stride 8 rows.
// ---------------------------------------------------------------------------
__global__ __launch_bounds__(256)
void a1_pass(const float* __restrict__ qt, const float* __restrict__ v,
             const float* __restrict__ wa_b, float* __restrict__ A1) {
  const int tid = threadIdx.x, lane = tid & 63, wave = tid >> 6;
  const float wab = wa_b[0];
  const float4* vp = (const float4*)(v + lane * 8);
  float4 vv0 = vp[0], vv1 = vp[1];
  const int gw = blockIdx.x * 4 + wave;       // 0..2047
  for (int r = gw; r < NQ; r += 2048) {
    const float4* p = (const float4*)(qt + (size_t)r * HD + lane * 8);
    float4 u = p[0], w = p[1];
    float dot = u.x * vv0.x + u.y * vv0.y + u.z * vv0.z + u.w * vv0.w
              + w.x * vv1.x + w.y * vv1.y + w.z * vv1.z + w.w * vv1.w;
    float ss  = u.x * u.x + u.y * u.y + u.z * u.z + u.w * u.w
              + w.x * w.x + w.y * w.y + w.z * w.z + w.w * w.w;
#pragma unroll
    for (int off = 32; off; off >>= 1) {
      dot += __shfl_xor(dot, off);
      ss  += __shfl_xor(ss, off);
    }
    if (lane == 0) A1[r] = dot / fmaxf(sqrtf(ss), 1e-12f) + wab;
  }
}

// ---------------------------------------------------------------------------
// Kernel 4: single block, 1024 threads. Exact rank-11469 select over A1 via
// 16 rounds of 2-bit greedy MSB binary search.
// ---------------------------------------------------------------------------
__global__ __launch_bounds__(1024)
void select_kernel(const float* __restrict__ A1, float* __restrict__ scf) {
  __shared__ unsigned wred1[16], wred2[16], wred3[16];
  __shared__ unsigned s_res;
  const int t = threadIdx.x, lane = t & 63, wave = t >> 6;
  unsigned kloc[16];
#pragma unroll 4
  for (int j = 0; j < 16; ++j) kloc[j] = mapf(A1[j * 1024 + t]);
  if (t == 0) s_res = 0u;
  __syncthreads();

  for (int b = 30; b >= 0; b -= 2) {
    const unsigned res = s_res;
    const unsigned t1 = res | (1u << b);
    const unsigned t2 = res | (2u << b);
    const unsigned t3 = res | (3u << b);
    unsigned c1 = 0, c2 = 0, c3 = 0;
#pragma unroll
    for (int j = 0; j < 16; ++j) {
      unsigned k = kloc[j];
      c1 += (k < t1); c2 += (k < t2); c3 += (k < t3);
    }
#pragma unroll
    for (int off = 32; off; off >>= 1) {
      c1 += __shfl_xor(c1, off);
      c2 += __shfl_xor(c2, off);
      c3 += __shfl_xor(c3, off);
    }
    if (lane == 0) { wred1[wave] = c1; wred2[wave] = c2; wred3[wave] = c3; }
    __syncthreads();
    if (t == 0) {
      unsigned C1 = 0, C2 = 0, C3 = 0;
      for (int w = 0; w < 16; ++w) { C1 += wred1[w]; C2 += wred2[w]; C3 += wred3[w]; }
      unsigned nr = res;
      if (C3 <= RANK_TARGET)      nr = t3;
      else if (C2 <= RANK_TARGET) nr = t2;
      else if (C1 <= RANK_TARGET) nr = t1;
      s_res = nr;
    }
    __syncthreads();
  }
  if (t == 0) {
    unsigned key = s_res;
    unsigned bits = (key & 0x80000000u) ? (key ^ 0x80000000u) : ~key;
    scf[0] = __uint_as_float(bits);
  }
}

// ---------------------------------------------------------------------------
// Kernel 5: e(r) = exp(thr(A1[r]) - thre) -> out_attn (unnormalized);
// z'[c] += e(r)*qt[r,c]; S += e(r) into scf[2].
// ---------------------------------------------------------------------------
__global__ __launch_bounds__(256)
void expz(const float* __restrict__ A1, const float* __restrict__ qt,
          float* __restrict__ scf, float* __restrict__ e_out,
          float* __restrict__ z) {
  __shared__ float vpart[4][512];
  __shared__ float esum[4];
  const int tid = threadIdx.x, lane = tid & 63, wave = tid >> 6;
  const float thre = scf[0];
  const int gw = blockIdx.x * 4 + wave;
  const int tw = gridDim.x * 4;
  float acc[8] = {0, 0, 0, 0, 0, 0, 0, 0};
  float es = 0.f;
  for (int r = gw; r < NQ; r += tw) {
    float x = A1[r]; x = (x > thre) ? x : 0.f;
    float e = expf(x - thre);
    if (lane == 0) e_out[r] = e;
    es += e;
    const float4* p = (const float4*)(qt + (size_t)r * HD + lane * 8);
    float4 u = p[0], w = p[1];
    acc[0] += e * u.x; acc[1] += e * u.y; acc[2] += e * u.z; acc[3] += e * u.w;
    acc[4] += e * w.x; acc[5] += e * w.y; acc[6] += e * w.z; acc[7] += e * w.w;
  }
  if (lane == 0) esum[wave] = es;   // es identical across lanes of the wave
#pragma unroll
  for (int j = 0; j < 8; ++j) vpart[wave][lane * 8 + j] = acc[j];
  __syncthreads();
  for (int c = tid; c < 512; c += 256)
    atomicAdd(&z[c], vpart[0][c] + vpart[1][c] + vpart[2][c] + vpart[3][c]);
  if (tid == 0) atomicAdd(&scf[2], esum[0] + esum[1] + esum[2] + esum[3]);
}

// ---------------------------------------------------------------------------
// Kernel 6: attn *= 1/S (blocks 0..63); block 64: y = (z'.cls_w)/S + cls_b.
// ---------------------------------------------------------------------------
__global__ __launch_bounds__(256)
void finalize(float* __restrict__ attn, const float* __restrict__ scf,
              const float* __restrict__ z, const float* __restrict__ cls_w,
              const float* __restrict__ cls_b, float* __restrict__ y) {
  const float invZ = 1.f / scf[2];
  if (blockIdx.x < 64) {
    int i = blockIdx.x * 256 + threadIdx.x;
    attn[i] *= invZ;
  } else if (threadIdx.x < 64) {
    const int lane = threadIdx.x;
    const float4* zp = (const float4*)(z + lane * 8);
    const float4* wp = (const float4*)(cls_w + lane * 8);
    float4 a = zp[0], b = zp[1], c = wp[0], d = wp[1];
    float dot = a.x * c.x + a.y * c.y + a.z * c.z + a.w * c.w
              + b.x * d.x + b.y * d.y + b.z * d.z + b.w * d.w;
#pragma unroll
    for (int off = 32; off; off >>= 1) dot += __shfl_xor(dot, off);
    if (lane == 0) y[0] = dot * invZ + cls_b[0];
  }
}

// ---------------------------------------------------------------------------
// Workspace layout (bytes). Max end = 52,498,688. No qbf, no A1dot/A1ss.
// v/z/scf contiguous (zeroed as 1088 uints by conv_wk block 0).
// ---------------------------------------------------------------------------
#define OFF_WQBF 0u
#define OFF_WKBF 1048576u
#define OFF_KBF  2097152u      // 16.25 MB, ends 18,343,936
#define OFF_QT   18874368u     // 33.55 MB, ends 52,428,800
#define OFF_A1   52428800u     // 64 KB... (A1 is 16384*4 = 64 KB) -> see below
#define OFF_V    52494336u     // 2 KB
#define OFF_Z    52496384u     // 2 KB
#define OFF_SC   52498432u     // 256 B, ends 52,498,688

extern "C" void kernel_launch(void* const* d_in, const int* in_sizes, int n_in,
                              void* d_out, int out_size, void* d_ws, size_t ws_size,
                              hipStream_t stream) {
  const float* query = (const float*)d_in[0];
  const float* key_x = (const float*)d_in[1];
  const float* wq_w  = (const float*)d_in[2];
  const float* wq_b  = (const float*)d_in[3];
  const float* wk_w  = (const float*)d_in[4];
  const float* wk_b  = (const float*)d_in[5];
  const float* wa_w  = (const float*)d_in[6];
  const float* wa_b  = (const float*)d_in[7];
  const float* cls_w = (const float*)d_in[8];
  const float* cls_b = (const float*)d_in[9];
  float* out = (float*)d_out;

  char* ws = (char*)d_ws;
  __bf16* wqbf  = (__bf16*)(ws + OFF_WQBF);
  __bf16* wkbf  = (__bf16*)(ws + OFF_WKBF);
  __bf16* kbf   = (__bf16*)(ws + OFF_KBF);
  float*  qtanh = (float*)(ws + OFF_QT);
  float*  A1    = (float*)(ws + OFF_A1);
  float*  v     = (float*)(ws + OFF_V);
  float*  z     = (float*)(ws + OFF_Z);
  float*  scf   = (float*)(ws + OFF_SC);
  float*  out_attn = out + 1;

  // 1: convert key + weights to bf16; zero v/z/scf
  conv_wk<<<2048, 256, 0, stream>>>(wq_w, wk_w, key_x, wqbf, wkbf, kbf,
                                    (unsigned*)v);

  // 2: mega launch — k-GEMM (fused v) co-scheduled with q-GEMM (qtanh)
  mega_gemms<<<636, 512, 0, stream>>>(kbf, wkbf, wk_b, wa_w, v,
                                      query, wqbf, wq_b, qtanh);

  // 3: A1 from qtanh and v (BW pass)
  a1_pass<<<512, 256, 0, stream>>>(qtanh, v, wa_b, A1);

  // 4: exact rank-11469 threshold (single block)
  select_kernel<<<1, 1024, 0, stream>>>(A1, scf);

  // 5: e(r), z' accumulation, S
  expz<<<256, 256, 0, stream>>>(A1, qtanh, scf, out_attn, z);

  // 6: normalize attn; y
  finalize<<<65, 256, 0, stream>>>(out_attn, scf, z, cls_w, cls_b, out);
}